// Round 1
// baseline (112.252 us; speedup 1.0000x reference)
//
#include <hip/hip_runtime.h>
#include <hip/hip_bf16.h>
#include <stdint.h>

#define IN_F   128
#define OUT_F  128
#define NUM_F  8
#define NROWS  (16*4096)

typedef __bf16  bf16x8  __attribute__((ext_vector_type(8)));
typedef float   f32x16  __attribute__((ext_vector_type(16)));

// W_perm: 9 feature-blocks x 8 k-steps x 4 n-tiles x 64 lanes x 8 bf16 = 294912 B
#define WP_CHUNKS (9*8*4*64)
#define WP_BYTES  (WP_CHUNKS*16)
#define BIAS_OFF  WP_BYTES

// ---------------- prep: build permuted bf16 weight + bias ----------------
__global__ __launch_bounds__(256) void skan_prep(
    const float* __restrict__ base_w,   // [OUT_F][IN_F]
    const float* __restrict__ scale,    // [OUT_F]
    const float* __restrict__ coef,     // [GROUPS][1][NUM_F]
    const float* __restrict__ conv_w,   // [NUM_F][OUT_F][IN_F]
    const float* __restrict__ conv_b,   // [NUM_F][OUT_F]
    __bf16* __restrict__ Wp, float* __restrict__ bias)
{
    int gid = blockIdx.x * 256 + threadIdx.x;        // 0..18431 chunk id
    int l  = gid & 63;
    int t  = (gid >> 6) & 3;
    int s  = (gid >> 8) & 7;
    int fb = gid >> 11;                              // 0..8
    int n  = t * 32 + (l & 31);
    int k0 = s * 16 + (l >> 5) * 8;
    __bf16* dst = Wp + (size_t)gid * 8;
    if (fb == 0) {
        #pragma unroll
        for (int j = 0; j < 8; ++j)
            dst[j] = (__bf16)base_w[n * IN_F + k0 + j];
    } else {
        int f = fb - 1;
        float sc = scale[n];
        #pragma unroll
        for (int j = 0; j < 8; ++j) {
            int k = k0 + j;
            float v = conv_w[((size_t)f * OUT_F + n) * IN_F + k]
                      * coef[(k >> 4) * NUM_F + f] * sc;
            dst[j] = (__bf16)v;
        }
    }
    if (gid < OUT_F) {
        float b = 0.f;
        #pragma unroll
        for (int f = 0; f < NUM_F; ++f) b += conv_b[f * OUT_F + gid];
        bias[gid] = b * scale[gid];
    }
}

// ---------------- main fused kernel ----------------
__device__ __forceinline__ void gld_lds16(const void* g, void* l) {
    __builtin_amdgcn_global_load_lds(
        (const __attribute__((address_space(1))) uint32_t*)g,
        (__attribute__((address_space(3))) uint32_t*)l, 16, 0, 0);
}

__global__ __launch_bounds__(256, 2) void skan_main(
    const float* __restrict__ x,        // [NROWS][IN_F]
    const __bf16* __restrict__ Wp,
    const float* __restrict__ bias,
    float* __restrict__ out)            // [NROWS][OUT_F]
{
    __shared__ uint4 smem4[2048];       // 32 KB, 16B-aligned
    char* smem = (char*)smem4;

    const int tid = threadIdx.x;
    const int w   = tid >> 6;           // wave 0..3
    const int l   = tid & 63;
    const int hl  = l & 31;
    const int h   = l >> 5;
    const int m0  = blockIdx.x * 128 + w * 32;   // wave's row base
    const int m   = m0 + hl;                     // this lane's row (A operand)

    // ---- load this lane's 64 x elements in A-fragment order ----
    // element (s,j): col = s*16 + h*8 + j
    const float4* x4 = (const float4*)x + (size_t)m * (IN_F / 4) + 2 * h;
    float xe[64];
    #pragma unroll
    for (int s = 0; s < 8; ++s) {
        float4 a = x4[4 * s];
        float4 b = x4[4 * s + 1];
        xe[8*s+0] = a.x; xe[8*s+1] = a.y; xe[8*s+2] = a.z; xe[8*s+3] = a.w;
        xe[8*s+4] = b.x; xe[8*s+5] = b.y; xe[8*s+6] = b.z; xe[8*s+7] = b.w;
    }

    f32x16 acc[4];
    #pragma unroll
    for (int t = 0; t < 4; ++t)
        #pragma unroll
        for (int r = 0; r < 16; ++r) acc[t][r] = 0.f;

    const bf16x8* bp = (const bf16x8*)smem;
    const char* wpb  = (const char*)Wp;

    for (int fb = 0; fb < 9; ++fb) {
        __syncthreads();   // previous block's LDS reads done
        // stage W block fb (32 KB) via async global->LDS, 16B/lane
        {
            const char* src = wpb + (size_t)fb * 32768;
            #pragma unroll
            for (int r = 0; r < 8; ++r) {
                int off = (r * 4 + w) * 1024;
                gld_lds16(src + off + l * 16, smem + off);
            }
        }
        // compute A fragments (VALU, overlaps the in-flight loads)
        bf16x8 af[8];
        if (fb == 0) {
            #pragma unroll
            for (int s = 0; s < 8; ++s)
                #pragma unroll
                for (int j = 0; j < 8; ++j) {
                    float v = xe[8*s+j];
                    float sv = v * __builtin_amdgcn_rcpf(1.0f + __expf(-v));
                    af[s][j] = (__bf16)sv;
                }
        } else {
            float cf = (float)fb * 0.15915494309189535f;  // fb/(2*pi)
            #pragma unroll
            for (int s = 0; s < 8; ++s)
                #pragma unroll
                for (int j = 0; j < 8; ++j) {
                    float a = __builtin_amdgcn_fractf(cf * xe[8*s+j]);
                    af[s][j] = (__bf16)__builtin_amdgcn_sinf(a);
                }
        }
        __syncthreads();   // staging complete (barrier drains vmcnt)
        #pragma unroll
        for (int s = 0; s < 8; ++s) {
            #pragma unroll
            for (int t = 0; t < 4; ++t) {
                bf16x8 b = bp[(s * 4 + t) * 64 + l];
                acc[t] = __builtin_amdgcn_mfma_f32_32x32x16_bf16(af[s], b, acc[t], 0, 0, 0);
            }
        }
    }

    // ---- epilogue: D layout col = lane&31, row = (reg&3) + 8*(reg>>2) + 4*(lane>>5)
    #pragma unroll
    for (int t = 0; t < 4; ++t) {
        float bv = bias[t * 32 + hl];
        #pragma unroll
        for (int r = 0; r < 16; ++r) {
            int row = (r & 3) + 8 * (r >> 2) + 4 * h;
            out[(size_t)(m0 + row) * OUT_F + t * 32 + hl] = acc[t][r] + bv;
        }
    }
}

extern "C" void kernel_launch(void* const* d_in, const int* in_sizes, int n_in,
                              void* d_out, int out_size, void* d_ws, size_t ws_size,
                              hipStream_t stream) {
    const float* x      = (const float*)d_in[0];
    // d_in[1] = grid (values 1..8, folded into the per-block frequency)
    const float* base_w = (const float*)d_in[2];
    const float* scale  = (const float*)d_in[3];
    const float* coef   = (const float*)d_in[4];
    const float* conv_w = (const float*)d_in[5];
    const float* conv_b = (const float*)d_in[6];
    __bf16* Wp   = (__bf16*)d_ws;
    float*  bias = (float*)((char*)d_ws + BIAS_OFF);
    float*  out  = (float*)d_out;

    skan_prep<<<WP_CHUNKS / 256, 256, 0, stream>>>(base_w, scale, coef, conv_w, conv_b, Wp, bias);
    skan_main<<<NROWS / 128, 256, 0, stream>>>(x, Wp, bias, out);
}